// Round 2
// baseline (1906.684 us; speedup 1.0000x reference)
//
#include <hip/hip_runtime.h>

// ---------------------------------------------------------------------------
// AdderNet 6-layer stack on MI355X (gfx950).
// out[n,o,p] = -sum_k |patch[p,k] - w[o,k]|   (VALU-bound; no MFMA possible)
// BN(batch stats)+ReLU6 of layer i folded into layer i+1's staging load.
//
// R2: 8x8 micro-tile (128 pix x 128 outch per 256-thr block), tap-major
// im2col k-order (chunk-uniform tap decode), swizzled xs LDS (2-way max).
// ---------------------------------------------------------------------------

template <bool IS3x3>
__global__ __launch_bounds__(256, 3)
void adder_conv(const float* __restrict__ x, const float* __restrict__ wT,
                const float2* __restrict__ ab, float* __restrict__ out,
                int Cin, int H, int W, int Wo, int Cout,
                int stride, int pad, int chunks, int P, int PI)
{
    constexpr int KC = 32;
    // xs: 16 pixel-groups of 8 floats at stride 12 words -> b128 reads 2-way max
    __shared__ float xs[KC][192];
    __shared__ float ws[KC][128];
    const int t  = threadIdx.x;
    const int tx = t & 15, ty = t >> 4;           // micro-tile coords
    const int ptile = blockIdx.x * 128, otile = blockIdx.y * 128;
    const int pp = t & 127, rg = t >> 7;          // staging: pixel col, k-row group

    // staging pixel decode (fixed per thread)
    const int p_st = ptile + pp;
    const bool pv = p_st < P;
    int n_st = 0, q = 0;
    if (pv) { n_st = p_st / PI; q = p_st - n_st * PI; }
    const int oh = q / Wo, ow = q - oh * Wo;
    const int ih0 = oh * stride - pad, iw0 = ow * stride - pad;
    const int HWi = H * W;
    const float* xb = x + (size_t)n_st * Cin * HWi;
    const bool hasBN = (ab != nullptr);
    const int xcol = (pp >> 3) * 12 + (pp & 7);   // swizzled column

    float acc[8][8] = {};

    for (int ch = blockIdx.z; ch < chunks; ch += gridDim.z) {
        const int k0 = ch * KC;
        int c0, ih, iw;
        if (IS3x3) {
            const int tap = k0 / Cin;             // uniform per chunk (Cin%32==0)
            c0 = k0 - tap * Cin;
            const int kh = tap / 3, kw = tap - kh * 3;
            ih = ih0 + kh; iw = iw0 + kw;
        } else { c0 = k0; ih = ih0; iw = iw0; }
        const bool valid = pv && (!IS3x3 || (ih >= 0 && ih < H && iw >= 0 && iw < W));
        const float* px = xb + (size_t)(c0 + rg) * HWi + (ih * W + iw);

        // ---- stage activations: 16 elems/thread, stride 2*HW pointer walk.
        //      Padding / OOB positions stage literal 0 (reference semantics).
#pragma unroll
        for (int j = 0; j < KC / 2; ++j) {
            const int kk = j * 2 + rg;
            float v = 0.f;
            if (valid) {
                v = px[(size_t)(2 * j) * HWi];
                if (hasBN) {
                    const float2 s = ab[c0 + rg + 2 * j];
                    v = fminf(fmaxf(fmaf(s.x, v, s.y), 0.f), 6.f);
                }
            }
            xs[kk][xcol] = v;
        }
        // ---- stage weights ([k][Cout] pre-transposed, tap-major rows)
        const float* pw = wT + (size_t)(k0 + rg) * Cout + otile + pp;
#pragma unroll
        for (int j = 0; j < KC / 2; ++j)
            ws[j * 2 + rg][pp] = pw[(size_t)(2 * j) * Cout];
        __syncthreads();

        // ---- inner: 4 ds_read_b128 + 128 VALU (sub + abs-add) per k
#pragma unroll 2
        for (int kk = 0; kk < KC; ++kk) {
            const float4 a0 = *(const float4*)&xs[kk][tx * 12];
            const float4 a1 = *(const float4*)&xs[kk][tx * 12 + 4];
            const float4 b0 = *(const float4*)&ws[kk][ty * 8];
            const float4 b1 = *(const float4*)&ws[kk][ty * 8 + 4];
            const float xa[8] = {a0.x, a0.y, a0.z, a0.w, a1.x, a1.y, a1.z, a1.w};
            const float wb[8] = {b0.x, b0.y, b0.z, b0.w, b1.x, b1.y, b1.z, b1.w};
#pragma unroll
            for (int i = 0; i < 8; ++i)
#pragma unroll
                for (int jj = 0; jj < 8; ++jj)
                    acc[i][jj] += fabsf(xa[i] - wb[jj]);
        }
        __syncthreads();
    }

    // ---- split-K atomic accumulate into pre-zeroed buffer (negated here)
#pragma unroll
    for (int i = 0; i < 8; ++i) {
        const int p = ptile + tx * 8 + i;
        if (p >= P) continue;
        const int n = p / PI, qq = p - n * PI;
        float* orow = out + ((size_t)n * Cout + otile) * PI + qq;
#pragma unroll
        for (int jj = 0; jj < 8; ++jj)
            unsafeAtomicAdd(&orow[(size_t)(ty * 8 + jj) * PI], -acc[i][jj]);
    }
}

// per-(channel, image) partial stats -> f64 atomics into zeroed st[2C]
__global__ void stats_kernel(const float* __restrict__ y, double* __restrict__ st,
                             int C, int PI)
{
    const int c = blockIdx.x, n = blockIdx.y, t = threadIdx.x;
    const float* row = y + ((size_t)n * C + c) * PI;
    double s = 0.0, s2 = 0.0;
    for (int qq = t; qq < PI; qq += 256) {
        const float v = row[qq];
        s += v; s2 += (double)v * v;
    }
    __shared__ double sh[256], sh2[256];
    sh[t] = s; sh2[t] = s2; __syncthreads();
    for (int off = 128; off > 0; off >>= 1) {
        if (t < off) { sh[t] += sh[t + off]; sh2[t] += sh2[t + off]; }
        __syncthreads();
    }
    if (t == 0) {
        unsafeAtomicAdd(&st[2 * c], sh[0]);
        unsafeAtomicAdd(&st[2 * c + 1], sh2[0]);
    }
}

// per-channel affine fold: a = g*rsqrt(var+eps), b = beta - mean*a
__global__ void ab_kernel(const double* __restrict__ st, const float* __restrict__ gamma,
                          const float* __restrict__ beta, float2* __restrict__ ab,
                          int C, double invCount)
{
    const int c = blockIdx.x * blockDim.x + threadIdx.x;
    if (c < C) {
        const double mean = st[2 * c] * invCount;
        const double var  = st[2 * c + 1] * invCount - mean * mean;
        const float a = gamma[c] * rsqrtf((float)var + 1e-5f);
        const float b = beta[c] - (float)mean * a;
        ab[c] = make_float2(a, b);
    }
}

// final BN+ReLU6 -> d_out
__global__ void apply_kernel(const float* __restrict__ y, const float2* __restrict__ ab,
                             float* __restrict__ out, int total, int C, int PI)
{
    const int i = blockIdx.x * 256 + threadIdx.x;
    if (i < total) {
        const int c = (i / PI) % C;
        const float2 s = ab[c];
        out[i] = fminf(fmaxf(fmaf(s.x, y[i], s.y), 0.f), 6.f);
    }
}

// w [Cout][Cin][kh][kw] -> wT [tap*Cin + c][Cout]  (tap-major k order)
__global__ void transpose_w(const float* __restrict__ w, float* __restrict__ wT,
                            int Cout, int Cin, int KhKw)
{
    const int i = blockIdx.x * 256 + threadIdx.x;
    const int K = Cin * KhKw;
    if (i < Cout * K) {
        const int k = i / Cout, o = i - k * Cout;
        const int tap = k / Cin, c = k - tap * Cin;
        wT[i] = w[((size_t)o * Cin + c) * KhKw + tap];
    }
}

extern "C" void kernel_launch(void* const* d_in, const int* in_sizes, int n_in,
                              void* d_out, int out_size, void* d_ws, size_t ws_size,
                              hipStream_t stream)
{
    const float* x = (const float*)d_in[0];
    const float *w[6], *g[6], *bt[6];
    for (int i = 0; i < 6; ++i) {
        w[i]  = (const float*)d_in[1 + 3 * i];
        g[i]  = (const float*)d_in[2 + 3 * i];
        bt[i] = (const float*)d_in[3 + 3 * i];
    }

    char* ws = (char*)d_ws;
    float* bufA = (float*)ws;                                   // 5,914,624 f
    float* bufB = (float*)(ws + 23658496);                      // 2,957,312 f
    size_t off = 23658496 + 11829248;
    const int wElems[6] = {256 * 512, 512 * 2304, 128 * 512,
                           256 * 1152, 128 * 256, 256 * 1152};
    float* wT[6];
    for (int i = 0; i < 6; ++i) { wT[i] = (float*)(ws + off); off += (size_t)wElems[i] * 4; }
    double* st = (double*)(ws + off); off += 3072 * 8;
    float2* ab = (float2*)(ws + off);
    const int stOff[6] = {0, 512, 1536, 1792, 2304, 2560};
    const int abOff[6] = {0, 256, 768, 896, 1152, 1280};

    const dim3 blk(256);

    // zero the stats accumulators (ws is poisoned 0xAA before every launch)
    hipMemsetAsync(st, 0, 3072 * 8, stream);

    // weight transposes (tap-major)
    const int wCout[6] = {256, 512, 128, 256, 128, 256};
    const int wCin[6]  = {512, 256, 512, 128, 256, 128};
    const int wTap[6]  = {1, 9, 1, 9, 1, 9};
    for (int i = 0; i < 6; ++i)
        transpose_w<<<(wElems[i] + 255) / 256, blk, 0, stream>>>(w[i], wT[i], wCout[i], wCin[i], wTap[i]);

    // ---- L1: 1x1, 512->256, 38x38, P=23104, K=512 (chunks=16)
    hipMemsetAsync(bufA, 0, (size_t)23104 * 256 * 4, stream);
    adder_conv<false><<<dim3(181, 2, 2), blk, 0, stream>>>(
        x, wT[0], nullptr, bufA, 512, 38, 38, 38, 256, 1, 0, 16, 23104, 1444);
    stats_kernel<<<dim3(256, 16), blk, 0, stream>>>(bufA, st + stOff[0], 256, 1444);
    ab_kernel<<<1, blk, 0, stream>>>(st + stOff[0], g[0], bt[0], ab + abOff[0], 256, 1.0 / 23104);

    // ---- L2: 3x3 s2 p1, 256->512, 38->19, P=5776, K=2304 (chunks=72)
    hipMemsetAsync(bufB, 0, (size_t)5776 * 512 * 4, stream);
    adder_conv<true><<<dim3(46, 4, 4), blk, 0, stream>>>(
        bufA, wT[1], ab + abOff[0], bufB, 256, 38, 38, 19, 512, 2, 1, 72, 5776, 361);
    stats_kernel<<<dim3(512, 16), blk, 0, stream>>>(bufB, st + stOff[1], 512, 361);
    ab_kernel<<<2, blk, 0, stream>>>(st + stOff[1], g[1], bt[1], ab + abOff[1], 512, 1.0 / 5776);

    // ---- L3: 1x1, 512->128, 19x19, P=5776, K=512 (chunks=16)
    hipMemsetAsync(bufA, 0, (size_t)5776 * 128 * 4, stream);
    adder_conv<false><<<dim3(46, 1, 8), blk, 0, stream>>>(
        bufB, wT[2], ab + abOff[1], bufA, 512, 19, 19, 19, 128, 1, 0, 16, 5776, 361);
    stats_kernel<<<dim3(128, 16), blk, 0, stream>>>(bufA, st + stOff[2], 128, 361);
    ab_kernel<<<1, blk, 0, stream>>>(st + stOff[2], g[2], bt[2], ab + abOff[2], 128, 1.0 / 5776);

    // ---- L4: 3x3 s2 p1, 128->256, 19->10, P=1600, K=1152 (chunks=36)
    hipMemsetAsync(bufB, 0, (size_t)1600 * 256 * 4, stream);
    adder_conv<true><<<dim3(13, 2, 12), blk, 0, stream>>>(
        bufA, wT[3], ab + abOff[2], bufB, 128, 19, 19, 10, 256, 2, 1, 36, 1600, 100);
    stats_kernel<<<dim3(256, 16), blk, 0, stream>>>(bufB, st + stOff[3], 256, 100);
    ab_kernel<<<1, blk, 0, stream>>>(st + stOff[3], g[3], bt[3], ab + abOff[3], 256, 1.0 / 1600);

    // ---- L5: 1x1, 256->128, 10x10, P=1600, K=256 (chunks=8)
    hipMemsetAsync(bufA, 0, (size_t)1600 * 128 * 4, stream);
    adder_conv<false><<<dim3(13, 1, 8), blk, 0, stream>>>(
        bufB, wT[4], ab + abOff[3], bufA, 256, 10, 10, 10, 128, 1, 0, 8, 1600, 100);
    stats_kernel<<<dim3(128, 16), blk, 0, stream>>>(bufA, st + stOff[4], 128, 100);
    ab_kernel<<<1, blk, 0, stream>>>(st + stOff[4], g[4], bt[4], ab + abOff[4], 128, 1.0 / 1600);

    // ---- L6: 3x3 s2 p0, 128->256, 10->4, P=256, K=1152 (chunks=36)
    hipMemsetAsync(bufB, 0, (size_t)256 * 256 * 4, stream);
    adder_conv<true><<<dim3(2, 2, 36), blk, 0, stream>>>(
        bufA, wT[5], ab + abOff[4], bufB, 128, 10, 10, 4, 256, 2, 0, 36, 256, 16);
    stats_kernel<<<dim3(256, 16), blk, 0, stream>>>(bufB, st + stOff[5], 256, 16);
    ab_kernel<<<1, blk, 0, stream>>>(st + stOff[5], g[5], bt[5], ab + abOff[5], 256, 1.0 / 256);

    // ---- final BN+ReLU6 -> out
    apply_kernel<<<(65536 + 255) / 256, blk, 0, stream>>>(bufB, ab + abOff[5], (float*)d_out,
                                                          65536, 256, 16);
}

// Round 3
// 1061.966 us; speedup vs baseline: 1.7954x; 1.7954x over previous
//
#include <hip/hip_runtime.h>

// ---------------------------------------------------------------------------
// AdderNet 6-layer stack on MI355X (gfx950).
// out[n,o,p] = -sum_k |patch[p,k] - w[o,k]|   (VALU-bound; no MFMA possible)
// BN(batch stats)+ReLU6 of layer i folded into layer i+1's staging load.
//
// R3: 64pix x 128och tile, 4x8 micro (32 acc regs, fits 128-VGPR budget),
// NO conv atomics: split-K writes Z disjoint partial slices (plain float4
// stores), fused combine+stats kernel reduces slices + negates + BN stats.
// ---------------------------------------------------------------------------

template <bool IS3x3, bool BN>
__global__ __launch_bounds__(256, 4)
void adder_conv(const float* __restrict__ x, const float* __restrict__ wT,
                const float2* __restrict__ ab, float* __restrict__ part,
                int Cin, int H, int W, int Wo, int Cout,
                int stride, int pad, int cpz, int P, int PI, int Pp)
{
    constexpr int KC = 32;
    __shared__ float xs[KC][68];     // stride 68: conflict-light reads+writes
    __shared__ float ws[KC][128];
    __shared__ float2 abls[512];

    const int t  = threadIdx.x;
    const int tx = t & 15, ty = t >> 4;          // compute: 4 pix x 8 och
    const int ptile = blockIdx.x * 64, otile = blockIdx.y * 128;
    const int pp = t & 63, rg = t >> 6;          // xs staging: pixel, k-group
    const int oq = t & 31, kr = t >> 5;          // ws staging: och-quad, k-row

    if (BN) {
        for (int i = t; i < Cin; i += 256) abls[i] = ab[i];
        __syncthreads();
    }

    // staging pixel decode (fixed per thread)
    const int p_st = ptile + pp;
    const bool pv = p_st < P;
    int n_st = 0, q = 0;
    if (pv) { n_st = p_st / PI; q = p_st - n_st * PI; }
    const int oh = q / Wo, ow = q - oh * Wo;
    const int ih0 = oh * stride - pad, iw0 = ow * stride - pad;
    const int HWi = H * W;
    const float* xb = x + (size_t)n_st * Cin * HWi;

    float acc[4][8] = {};

    const int chunkBeg = blockIdx.z * cpz, chunkEnd = chunkBeg + cpz;
    for (int ch = chunkBeg; ch < chunkEnd; ++ch) {
        const int k0 = ch * KC;
        int c0, ih, iw;
        if (IS3x3) {
            const int tap = k0 / Cin;            // uniform per chunk (Cin%32==0)
            c0 = k0 - tap * Cin;
            const int kh = tap / 3, kw = tap - kh * 3;
            ih = ih0 + kh; iw = iw0 + kw;
        } else { c0 = k0; ih = ih0; iw = iw0; }
        const bool valid = pv && (!IS3x3 || (ih >= 0 && ih < H && iw >= 0 && iw < W));
        const float* px = xb + (size_t)(c0 + rg) * HWi + (ih * W + iw);

        // ---- stage activations: 8 elems/thread, stride 4*HW pointer walk.
        //      Padding / OOB positions stage literal 0 (reference semantics).
#pragma unroll
        for (int j = 0; j < KC / 4; ++j) {
            const int kk = rg + 4 * j;
            float v = 0.f;
            if (valid) {
                v = px[(size_t)(4 * j) * HWi];
                if (BN) {
                    const float2 s = abls[c0 + kk];
                    v = fminf(fmaxf(fmaf(s.x, v, s.y), 0.f), 6.f);
                }
            }
            xs[kk][pp] = v;
        }
        // ---- stage weights: float4 loads from wT [k][Cout], 4/thread
#pragma unroll
        for (int j = 0; j < 4; ++j) {
            const int kk = kr + 8 * j;
            const float4 wv = *(const float4*)&wT[(size_t)(k0 + kk) * Cout + otile + oq * 4];
            *(float4*)&ws[kk][oq * 4] = wv;
        }
        __syncthreads();

        // ---- inner: 3 ds_read_b128 + 64 VALU (sub + add-with-|mod|) per k
#pragma unroll 2
        for (int kk = 0; kk < KC; ++kk) {
            const float4 xv = *(const float4*)&xs[kk][tx * 4];
            const float4 wa = *(const float4*)&ws[kk][ty * 8];
            const float4 wb = *(const float4*)&ws[kk][ty * 8 + 4];
#define ACC1(I, XC)                                             \
            acc[I][0] += __builtin_fabsf(XC - wa.x);            \
            acc[I][1] += __builtin_fabsf(XC - wa.y);            \
            acc[I][2] += __builtin_fabsf(XC - wa.z);            \
            acc[I][3] += __builtin_fabsf(XC - wa.w);            \
            acc[I][4] += __builtin_fabsf(XC - wb.x);            \
            acc[I][5] += __builtin_fabsf(XC - wb.y);            \
            acc[I][6] += __builtin_fabsf(XC - wb.z);            \
            acc[I][7] += __builtin_fabsf(XC - wb.w);
            ACC1(0, xv.x) ACC1(1, xv.y) ACC1(2, xv.z) ACC1(3, xv.w)
#undef ACC1
        }
        __syncthreads();
    }

    // ---- plain coalesced stores into this z-slice's partial buffer
    const int p0 = ptile + tx * 4;
    const bool full = (p0 + 3) < P;
#pragma unroll
    for (int jj = 0; jj < 8; ++jj) {
        const int o = otile + ty * 8 + jj;
        float* dst = part + ((size_t)blockIdx.z * Cout + o) * Pp + p0;
        if (full) {
            *(float4*)dst = make_float4(acc[0][jj], acc[1][jj], acc[2][jj], acc[3][jj]);
        } else {
#pragma unroll
            for (int i = 0; i < 4; ++i)
                if (p0 + i < P) dst[i] = acc[i][jj];
        }
    }
}

// fused: sum Z partial slices, negate -> final layout [n][c][PI], and
// accumulate per-channel sum/sumsq (double) for BN stats.
__global__ void combine_stats(const float* __restrict__ part, float* __restrict__ fin,
                              double* __restrict__ st, int C, int PI, int Z, int Pp)
{
    const int c = blockIdx.x, n = blockIdx.y, t = threadIdx.x;
    const int pbase = n * PI;
    double s = 0.0, s2 = 0.0;
    for (int qq = t; qq < PI; qq += 256) {
        float v = 0.f;
        for (int z = 0; z < Z; ++z)
            v += part[((size_t)z * C + c) * Pp + pbase + qq];
        v = -v;
        fin[((size_t)n * C + c) * PI + qq] = v;
        s += v; s2 += (double)v * v;
    }
    __shared__ double sh[256], sh2[256];
    sh[t] = s; sh2[t] = s2; __syncthreads();
    for (int off = 128; off > 0; off >>= 1) {
        if (t < off) { sh[t] += sh[t + off]; sh2[t] += sh2[t + off]; }
        __syncthreads();
    }
    if (t == 0) {
        unsafeAtomicAdd(&st[2 * c], sh[0]);
        unsafeAtomicAdd(&st[2 * c + 1], sh2[0]);
    }
}

// per-channel affine fold: a = g*rsqrt(var+eps), b = beta - mean*a
__global__ void ab_kernel(const double* __restrict__ st, const float* __restrict__ gamma,
                          const float* __restrict__ beta, float2* __restrict__ ab,
                          int C, double invCount)
{
    const int c = blockIdx.x * blockDim.x + threadIdx.x;
    if (c < C) {
        const double mean = st[2 * c] * invCount;
        const double var  = st[2 * c + 1] * invCount - mean * mean;
        const float a = gamma[c] * rsqrtf((float)var + 1e-5f);
        const float b = beta[c] - (float)mean * a;
        ab[c] = make_float2(a, b);
    }
}

// final BN+ReLU6 -> d_out
__global__ void apply_kernel(const float* __restrict__ y, const float2* __restrict__ ab,
                             float* __restrict__ out, int total, int C, int PI)
{
    const int i = blockIdx.x * 256 + threadIdx.x;
    if (i < total) {
        const int c = (i / PI) % C;
        const float2 s = ab[c];
        out[i] = fminf(fmaxf(fmaf(s.x, y[i], s.y), 0.f), 6.f);
    }
}

// merged weight transposes: w [Cout][Cin][tap] -> wT [tap*Cin + c][Cout]
struct TDesc { const float* w; float* wT; int Cout; int Cin; int Tap; int elems; };
struct TPack { TDesc d[6]; };

__global__ void transpose_all(TPack p)
{
    const TDesc d = p.d[blockIdx.y];
    const int i = blockIdx.x * 256 + threadIdx.x;
    if (i < d.elems) {
        const int k = i / d.Cout, o = i - k * d.Cout;
        const int tap = k / d.Cin, c = k - tap * d.Cin;
        d.wT[i] = d.w[((size_t)o * d.Cin + c) * d.Tap + tap];
    }
}

extern "C" void kernel_launch(void* const* d_in, const int* in_sizes, int n_in,
                              void* d_out, int out_size, void* d_ws, size_t ws_size,
                              hipStream_t stream)
{
    const float* x = (const float*)d_in[0];
    const float *w[6], *g[6], *bt[6];
    for (int i = 0; i < 6; ++i) {
        w[i]  = (const float*)d_in[1 + 3 * i];
        g[i]  = (const float*)d_in[2 + 3 * i];
        bt[i] = (const float*)d_in[3 + 3 * i];
    }

    char* ws = (char*)d_ws;
    float* bufA = (float*)ws;                                   // 23,658,496 B
    float* bufB = (float*)(ws + 23658496);                      // 11,829,248 B
    float* part = (float*)(ws + 23658496 + 11829248);           // 23,658,496 B
    size_t off = 23658496 + 11829248 + 23658496;
    const int wElems[6] = {256 * 512, 512 * 2304, 128 * 512,
                           256 * 1152, 128 * 256, 256 * 1152};
    float* wT[6];
    for (int i = 0; i < 6; ++i) { wT[i] = (float*)(ws + off); off += (size_t)wElems[i] * 4; }
    double* st = (double*)(ws + off); off += 3072 * 8;
    float2* ab = (float2*)(ws + off);
    const int stOff[6] = {0, 512, 1536, 1792, 2304, 2560};
    const int abOff[6] = {0, 256, 768, 896, 1152, 1280};

    const dim3 blk(256);

    // zero stats accumulators (ws is poisoned 0xAA before every launch)
    hipMemsetAsync(st, 0, 3072 * 8, stream);

    // merged weight transposes (tap-major k order)
    TPack tp;
    const int wCout[6] = {256, 512, 128, 256, 128, 256};
    const int wCin[6]  = {512, 256, 512, 128, 256, 128};
    const int wTap[6]  = {1, 9, 1, 9, 1, 9};
    for (int i = 0; i < 6; ++i)
        tp.d[i] = TDesc{w[i], wT[i], wCout[i], wCin[i], wTap[i], wElems[i]};
    transpose_all<<<dim3((1179648 + 255) / 256, 6), blk, 0, stream>>>(tp);

    // ---- L1: 1x1, 512->256, 38x38, P=23104, K=512, Z=1 (722 blocks)
    adder_conv<false, false><<<dim3(361, 2, 1), blk, 0, stream>>>(
        x, wT[0], nullptr, part, 512, 38, 38, 38, 256, 1, 0, 16, 23104, 1444, 23104);
    combine_stats<<<dim3(256, 16), blk, 0, stream>>>(part, bufA, st + stOff[0], 256, 1444, 1, 23104);
    ab_kernel<<<1, blk, 0, stream>>>(st + stOff[0], g[0], bt[0], ab + abOff[0], 256, 1.0 / 23104);

    // ---- L2: 3x3 s2 p1, 256->512, 38->19, P=5776, K=2304, Z=2 (728 blocks)
    adder_conv<true, true><<<dim3(91, 4, 2), blk, 0, stream>>>(
        bufA, wT[1], ab + abOff[0], part, 256, 38, 38, 19, 512, 2, 1, 36, 5776, 361, 5776);
    combine_stats<<<dim3(512, 16), blk, 0, stream>>>(part, bufB, st + stOff[1], 512, 361, 2, 5776);
    ab_kernel<<<2, blk, 0, stream>>>(st + stOff[1], g[1], bt[1], ab + abOff[1], 512, 1.0 / 5776);

    // ---- L3: 1x1, 512->128, 19x19, P=5776, K=512, Z=8 (728 blocks)
    adder_conv<false, true><<<dim3(91, 1, 8), blk, 0, stream>>>(
        bufB, wT[2], ab + abOff[1], part, 512, 19, 19, 19, 128, 1, 0, 2, 5776, 361, 5776);
    combine_stats<<<dim3(128, 16), blk, 0, stream>>>(part, bufA, st + stOff[2], 128, 361, 8, 5776);
    ab_kernel<<<1, blk, 0, stream>>>(st + stOff[2], g[2], bt[2], ab + abOff[2], 128, 1.0 / 5776);

    // ---- L4: 3x3 s2 p1, 128->256, 19->10, P=1600, K=1152, Z=6 (300 blocks)
    adder_conv<true, true><<<dim3(25, 2, 6), blk, 0, stream>>>(
        bufA, wT[3], ab + abOff[2], part, 128, 19, 19, 10, 256, 2, 1, 6, 1600, 100, 1600);
    combine_stats<<<dim3(256, 16), blk, 0, stream>>>(part, bufB, st + stOff[3], 256, 100, 6, 1600);
    ab_kernel<<<1, blk, 0, stream>>>(st + stOff[3], g[3], bt[3], ab + abOff[3], 256, 1.0 / 1600);

    // ---- L5: 1x1, 256->128, 10x10, P=1600, K=256, Z=8 (200 blocks)
    adder_conv<false, true><<<dim3(25, 1, 8), blk, 0, stream>>>(
        bufB, wT[4], ab + abOff[3], part, 256, 10, 10, 10, 128, 1, 0, 1, 1600, 100, 1600);
    combine_stats<<<dim3(128, 16), blk, 0, stream>>>(part, bufA, st + stOff[4], 128, 100, 8, 1600);
    ab_kernel<<<1, blk, 0, stream>>>(st + stOff[4], g[4], bt[4], ab + abOff[4], 128, 1.0 / 1600);

    // ---- L6: 3x3 s2 p0, 128->256, 10->4, P=256, K=1152, Z=18 (144 blocks)
    adder_conv<true, true><<<dim3(4, 2, 18), blk, 0, stream>>>(
        bufA, wT[5], ab + abOff[4], part, 128, 10, 10, 4, 256, 2, 0, 2, 256, 16, 256);
    combine_stats<<<dim3(256, 16), blk, 0, stream>>>(part, bufB, st + stOff[5], 256, 16, 18, 256);
    ab_kernel<<<1, blk, 0, stream>>>(st + stOff[5], g[5], bt[5], ab + abOff[5], 256, 1.0 / 256);

    // ---- final BN+ReLU6 -> out
    apply_kernel<<<(65536 + 255) / 256, blk, 0, stream>>>(bufB, ab + abOff[5], (float*)d_out,
                                                          65536, 256, 16);
}